// Round 4
// baseline (397.834 us; speedup 1.0000x reference)
//
#include <hip/hip_runtime.h>

#define B_SZ 4
#define SEQ 4096
#define DIN 1024
#define DH 1024
#define DOUT 1024
#define NBLK 8
#define MTOK (B_SZ * SEQ)      // 16384 tokens
#define CHUNK 64
#define NCHUNK (SEQ / CHUNK)   // 64

typedef _Float16 half8 __attribute__((ext_vector_type(8)));
typedef _Float16 half4v __attribute__((ext_vector_type(4)));
typedef float f32x4 __attribute__((ext_vector_type(4)));

// async global->LDS, 16B per lane. LDS dest must be wave-uniform; HW scatters
// to base + lane*16 (so LDS tiles are UNPADDED and laid out in lane order).
__device__ __forceinline__ void gl_lds16(const void* g, void* l) {
  __builtin_amdgcn_global_load_lds((__attribute__((address_space(1))) void*)g,
                                   (__attribute__((address_space(3))) void*)l,
                                   16, 0, 0);
}

// ---------------------------------------------------------------- converts
__global__ __launch_bounds__(256) void cvt_x_kernel(const float* __restrict__ src,
                                                    _Float16* __restrict__ dst) {
  const int gid = blockIdx.x * 256 + threadIdx.x;   // one float4 per thread
  const float4 v = ((const float4*)src)[gid];
  half4v h;
  h[0] = (_Float16)v.x; h[1] = (_Float16)v.y; h[2] = (_Float16)v.z; h[3] = (_Float16)v.w;
  ((half4v*)dst)[gid] = h;
}

// all 4 weight transposes (fp32->fp16, [R][C] -> [C][R]) in ONE dispatch.
// tiles: [0,256) W_in, [256,512) W_out, [512,544) Wgx (8 z x 4), [544,576) Wga
__global__ __launch_bounds__(256)
void transpose_all(const float* __restrict__ Win, const float* __restrict__ Wout,
                   const float* __restrict__ Wgx, const float* __restrict__ Wga,
                   _Float16* __restrict__ WinT, _Float16* __restrict__ WoutT,
                   _Float16* __restrict__ WgxT, _Float16* __restrict__ WgaT) {
  __shared__ float tile[64][65];
  int t = blockIdx.x;
  const float* src; _Float16* dst; int C; size_t bo = 0;
  if (t < 256)      { src = Win;  dst = WinT;  C = 1024; }
  else if (t < 512) { src = Wout; dst = WoutT; C = 1024; t -= 256; }
  else if (t < 544) { int u = t - 512; src = Wgx; dst = WgxT; C = 128;
                      bo = (size_t)(u >> 2) * (128 * 128); t = u & 3; }
  else              { int u = t - 544; src = Wga; dst = WgaT; C = 128;
                      bo = (size_t)(u >> 2) * (128 * 128); t = u & 3; }
  const int nbx = C >> 6;
  const int r0 = (t / nbx) * 64, c0 = (t % nbx) * 64;
  const int tr = threadIdx.x >> 6, tc = threadIdx.x & 63;
#pragma unroll
  for (int i = 0; i < 64; i += 4)
    tile[tr + i][tc] = src[bo + (size_t)(r0 + tr + i) * C + c0 + tc];
  __syncthreads();
#pragma unroll
  for (int i = 0; i < 64; i += 4) {
    const int cc = i + tr;
    dst[bo + (size_t)(c0 + cc) * C + r0 + tc] = (_Float16)tile[tc][cc];
  }
}

// ---------------------------------------------------------------- GEMM (m97 recipe)
// C[M,N] = A[M,K] * Bt[N,K]^T + bias ; 128x128 tile, 4 waves, BK=64, f16 MFMA.
// Epilogue stores j-INNERMOST: 4 stores cover contiguous 64 elems -> full-line
// sector merge survives the concurrent main-loop L2 churn.
template <int OUT_F32>
__global__ __launch_bounds__(256)
void gemm_bt(const _Float16* __restrict__ A, const _Float16* __restrict__ Bt,
             const float* __restrict__ bias, void* __restrict__ C,
             int M, int N, int K) {
  __shared__ __align__(16) _Float16 As[128 * 64];
  __shared__ __align__(16) _Float16 Bs[128 * 64];
  const int tid = threadIdx.x;
  const int wave = tid >> 6, lane = tid & 63;
  const int m0 = blockIdx.x * 128, n0 = blockIdx.y * 128;
  const int wm = (wave >> 1) * 64, wn = (wave & 1) * 64;
  const int row = lane & 15, quad = lane >> 4;
  const int srow = lane >> 3, scol = (lane & 7) * 8;

  f32x4 acc[4][4] = {};
  for (int kt = 0; kt < K; kt += 64) {
#pragma unroll
    for (int ci = 0; ci < 4; ci++) {
      const int c = wave * 4 + ci;
      gl_lds16(A  + (size_t)(m0 + c * 8 + srow) * K + kt + scol, As + c * 512);
      gl_lds16(Bt + (size_t)(n0 + c * 8 + srow) * K + kt + scol, Bs + c * 512);
    }
    __syncthreads();
#pragma unroll
    for (int kk = 0; kk < 64; kk += 32) {
      half8 af[4], bf[4];
#pragma unroll
      for (int i = 0; i < 4; i++)
        af[i] = *(const half8*)&As[(wm + i * 16 + row) * 64 + kk + quad * 8];
#pragma unroll
      for (int i = 0; i < 4; i++)
        bf[i] = *(const half8*)&Bs[(wn + i * 16 + row) * 64 + kk + quad * 8];
#pragma unroll
      for (int i = 0; i < 4; i++)
#pragma unroll
        for (int j = 0; j < 4; j++)
          acc[i][j] = __builtin_amdgcn_mfma_f32_16x16x32_f16(af[i], bf[j], acc[i][j], 0, 0, 0);
    }
    __syncthreads();
  }
  float bv[4];
#pragma unroll
  for (int j = 0; j < 4; j++) bv[j] = bias[n0 + wn + j * 16 + row];
#pragma unroll
  for (int i = 0; i < 4; i++) {
#pragma unroll
    for (int r = 0; r < 4; r++) {
      const int m = m0 + wm + i * 16 + quad * 4 + r;
      const size_t base = (size_t)m * N + n0 + wn + row;
#pragma unroll
      for (int j = 0; j < 4; j++) {
        const float v = acc[i][j][r] + bv[j];
        if (OUT_F32) ((float*)C)[base + j * 16] = v;
        else         ((_Float16*)C)[base + j * 16] = (_Float16)v;
      }
    }
  }
}

// ---------------------------------------------------------------- gates v2
// One block = 128 tokens x one 128-ch diag gate block. ZERO LDS, zero barriers:
// A-frags + xv read from global (32KB tile + 64KB weights, L1/L2-hit),
// VGPR capped for 16 waves/CU. Fused chunk-reduction (scan p1) + inline
// softplus + j-inner full-line stores.
__global__ __launch_bounds__(256, 4)
void gates_v2(const _Float16* __restrict__ xp,
              const _Float16* __restrict__ WxT, const _Float16* __restrict__ WaT,
              const float* __restrict__ bgx, const float* __restrict__ bga,
              const float* __restrict__ arp,
              _Float16* __restrict__ a_out, _Float16* __restrict__ gx_out,
              float* __restrict__ cA, float* __restrict__ cH) {
  const int tid = threadIdx.x;
  const int wave = tid >> 6, lane = tid & 63;
  const int m0 = blockIdx.x * 128, nb = blockIdx.y;
  const int wm = (wave >> 1) * 64, wn = (wave & 1) * 64;
  const int row = lane & 15, quad = lane >> 4;
  const _Float16* WxB = WxT + (size_t)nb * (128 * 128);
  const _Float16* WaB = WaT + (size_t)nb * (128 * 128);
  const _Float16* xb = xp + (size_t)m0 * DH + nb * 128;   // block's xp tile

  f32x4 accx[4][4] = {}, acca[4][4] = {};
#pragma unroll
  for (int kk = 0; kk < 128; kk += 32) {
    half8 af[4];
#pragma unroll
    for (int i = 0; i < 4; i++)
      af[i] = *(const half8*)&xb[(size_t)(wm + i * 16 + row) * DH + kk + quad * 8];
#pragma unroll
    for (int j = 0; j < 4; j++) {
      const size_t wo = (size_t)(wn + j * 16 + row) * 128 + kk + quad * 8;
      const half8 bx = *(const half8*)&WxB[wo];
      const half8 ba = *(const half8*)&WaB[wo];
#pragma unroll
      for (int i = 0; i < 4; i++) {
        accx[i][j] = __builtin_amdgcn_mfma_f32_16x16x32_f16(af[i], bx, accx[i][j], 0, 0, 0);
        acca[i][j] = __builtin_amdgcn_mfma_f32_16x16x32_f16(af[i], ba, acca[i][j], 0, 0, 0);
      }
    }
  }

  // epilogue: gate math + fused per-chunk (A,h) reduction (replaces scan p1)
  const int b_idx = (m0 + wm) >> 12;
  const int c_idx = ((m0 + wm) & (SEQ - 1)) >> 6;
  float bxv[4], bav[4], cd[4];
#pragma unroll
  for (int j = 0; j < 4; j++) {
    const int d = nb * 128 + wn + j * 16 + row;
    bxv[j] = bgx[d]; bav[j] = bga[d];
    cd[j] = log1pf(expf(arp[d]));   // softplus inline
  }
  float Arun[4], Hrun[4];
#pragma unroll
  for (int j = 0; j < 4; j++) { Arun[j] = 1.f; Hrun[j] = 0.f; }

#pragma unroll
  for (int i = 0; i < 4; i++) {
    float Aseg[4], Hseg[4];
#pragma unroll
    for (int j = 0; j < 4; j++) { Aseg[j] = 1.f; Hseg[j] = 0.f; }
#pragma unroll
    for (int r = 0; r < 4; r++) {
      const int tl = wm + i * 16 + quad * 4 + r;
      const size_t rowbase = (size_t)(m0 + tl) * DH + nb * 128 + wn + row;
      _Float16 ah[4], gh[4];
#pragma unroll
      for (int j = 0; j < 4; j++) {
        const float px = accx[i][j][r] + bxv[j];
        const float pa = acca[i][j][r] + bav[j];
        const float sx = 1.f / (1.f + __expf(-px));
        const float sa = 1.f / (1.f + __expf(-pa));
        const float a = __expf(-8.f * sa * cd[j]);
        const float n2 = fmaxf(1.f - a * a, 0.f);
        const float xv = (float)xb[(size_t)tl * DH + wn + j * 16 + row];
        ah[j] = (_Float16)a;
        gh[j] = (_Float16)(sx * xv * sqrtf(n2));
        const float ar = (float)ah[j], gr = (float)gh[j];   // rounded, matches p3
        Aseg[j] *= ar;
        Hseg[j] = fmaf(ar, Hseg[j], gr);
      }
#pragma unroll
      for (int j = 0; j < 4; j++) a_out[rowbase + j * 16] = ah[j];
#pragma unroll
      for (int j = 0; j < 4; j++) gx_out[rowbase + j * 16] = gh[j];
    }
    // cross-quad combine (token order q0..q3), fold into running
#pragma unroll
    for (int j = 0; j < 4; j++) {
      float A1 = Aseg[j], H1 = Hseg[j];
      float A2 = __shfl_down(A1, 16, 64), H2 = __shfl_down(H1, 16, 64);
      H1 = fmaf(A2, H1, H2); A1 *= A2;
      A2 = __shfl_down(A1, 32, 64); H2 = __shfl_down(H1, 32, 64);
      H1 = fmaf(A2, H1, H2); A1 *= A2;
      Hrun[j] = fmaf(A1, Hrun[j], H1);
      Arun[j] *= A1;
    }
  }
  if (lane < 16) {   // layout: cA[g][c], g = b*DH+d  (coalesced wave-scan in p2)
#pragma unroll
    for (int j = 0; j < 4; j++) {
      const int d = nb * 128 + wn + j * 16 + lane;
      const size_t base = ((size_t)(b_idx * DH + d)) * NCHUNK + c_idx;
      cA[base] = Arun[j];
      cH[base] = Hrun[j];
    }
  }
}

// ---------------------------------------------------------------- scan p2/p3
// p2: one wave per channel g; lane = chunk. 6-step shfl inclusive scan with
// segment composition (A2*A1, A2*H1+H2); exclusive shift gives chunk carry-in.
__global__ __launch_bounds__(256)
void scan_p2(const float* __restrict__ cA, const float* __restrict__ cH,
             const float* __restrict__ h0, float* __restrict__ cin,
             float* __restrict__ hlast) {
  const int wave = threadIdx.x >> 6, lane = threadIdx.x & 63;
  const int g = blockIdx.x * 4 + wave;   // [0, B_SZ*DH)
  float A = cA[(size_t)g * 64 + lane], H = cH[(size_t)g * 64 + lane];
#pragma unroll
  for (int d = 1; d < 64; d <<= 1) {
    const float Ap = __shfl_up(A, d, 64), Hp = __shfl_up(H, d, 64);
    if (lane >= d) { H = fmaf(A, Hp, H); A *= Ap; }
  }
  const float h0g = h0[g];
  if (lane == 63) hlast[g] = fmaf(A, h0g, H);
  float Ae = __shfl_up(A, 1, 64), He = __shfl_up(H, 1, 64);
  if (lane == 0) { Ae = 1.f; He = 0.f; }
  cin[(size_t)g * 64 + lane] = fmaf(Ae, h0g, He);
}

__global__ __launch_bounds__(256)
void scan_p3(const _Float16* __restrict__ a, const _Float16* __restrict__ gx,
             const float* __restrict__ cin, _Float16* __restrict__ h) {
  const int gtid = blockIdx.x * 256 + threadIdx.x;
  const int d = gtid & (DH - 1);
  const int bc = gtid >> 10;
  const int b = bc >> 6, c = bc & (NCHUNK - 1);
  const size_t base = ((size_t)(b * SEQ + c * CHUNK)) * DH + d;
  float carry = cin[((size_t)(b * DH + d)) * NCHUNK + c];
#pragma unroll 4
  for (int i = 0; i < CHUNK; i++) {
    const float av = (float)a[base + (size_t)i * DH];
    const float gv = (float)gx[base + (size_t)i * DH];
    carry = fmaf(av, carry, gv);
    h[base + (size_t)i * DH] = (_Float16)carry;
  }
}

// ---------------------------------------------------------------- launch
extern "C" void kernel_launch(void* const* d_in, const int* in_sizes, int n_in,
                              void* d_out, int out_size, void* d_ws, size_t ws_size,
                              hipStream_t stream) {
  const float* x     = (const float*)d_in[0];
  const float* h0    = (const float*)d_in[1];
  const float* W_in  = (const float*)d_in[2];
  const float* b_in  = (const float*)d_in[3];
  const float* Wgx   = (const float*)d_in[4];
  const float* bgx   = (const float*)d_in[5];
  const float* Wga   = (const float*)d_in[6];
  const float* bga   = (const float*)d_in[7];
  const float* arp   = (const float*)d_in[8];
  const float* W_out = (const float*)d_in[9];
  const float* b_out = (const float*)d_in[10];
  float* out = (float*)d_out;
  float* hlast = out + (size_t)MTOK * DOUT;

  char* p = (char*)d_ws;
  auto take = [&](size_t bytes) { char* r = p; p += (bytes + 255) & ~(size_t)255; return r; };
  _Float16* x_h   = (_Float16*)take((size_t)MTOK * DIN * 2);   // reused as h_buf
  _Float16* xp    = (_Float16*)take((size_t)MTOK * DH * 2);
  _Float16* a_buf = (_Float16*)take((size_t)MTOK * DH * 2);
  _Float16* gxb   = (_Float16*)take((size_t)MTOK * DH * 2);
  _Float16* WinT  = (_Float16*)take((size_t)DIN * DH * 2);
  _Float16* WoutT = (_Float16*)take((size_t)DH * DOUT * 2);
  _Float16* WgxT  = (_Float16*)take((size_t)NBLK * 128 * 128 * 2);
  _Float16* WgaT  = (_Float16*)take((size_t)NBLK * 128 * 128 * 2);
  float* cA   = (float*)take((size_t)NCHUNK * B_SZ * DH * 4);
  float* cH   = (float*)take((size_t)NCHUNK * B_SZ * DH * 4);
  float* cin  = (float*)take((size_t)NCHUNK * B_SZ * DH * 4);
  _Float16* h_buf = x_h;   // x_h dead after gemm1

  cvt_x_kernel<<<MTOK * DIN / 1024, 256, 0, stream>>>(x, x_h);
  transpose_all<<<576, 256, 0, stream>>>(W_in, W_out, Wgx, Wga, WinT, WoutT, WgxT, WgaT);

  gemm_bt<0><<<dim3(MTOK / 128, DH / 128), 256, 0, stream>>>(x_h, WinT, b_in, xp, MTOK, DH, DIN);
  gates_v2<<<dim3(MTOK / 128, NBLK), 256, 0, stream>>>(
      xp, WgxT, WgaT, bgx, bga, arp, a_buf, gxb, cA, cH);
  scan_p2<<<(B_SZ * DH) / 4, 256, 0, stream>>>(cA, cH, h0, cin, hlast);
  scan_p3<<<(B_SZ * NCHUNK * DH) / 256, 256, 0, stream>>>(a_buf, gxb, cin, h_buf);
  gemm_bt<1><<<dim3(MTOK / 128, DOUT / 128), 256, 0, stream>>>(h_buf, WoutT, b_out, out, MTOK, DOUT, DH);
}

// Round 5
// 363.517 us; speedup vs baseline: 1.0944x; 1.0944x over previous
//
#include <hip/hip_runtime.h>

#define B_SZ 4
#define SEQ 4096
#define DIN 1024
#define DH 1024
#define DOUT 1024
#define NBLK 8
#define MTOK (B_SZ * SEQ)      // 16384 tokens
#define CHUNK 64
#define NCHUNK (SEQ / CHUNK)   // 64

typedef _Float16 half8 __attribute__((ext_vector_type(8)));
typedef _Float16 half4v __attribute__((ext_vector_type(4)));
typedef float f32x4 __attribute__((ext_vector_type(4)));

// async global->LDS, 16B per lane. LDS dest must be wave-uniform; HW scatters
// to base + lane*16 (so LDS tiles are UNPADDED and laid out in lane order).
__device__ __forceinline__ void gl_lds16(const void* g, void* l) {
  __builtin_amdgcn_global_load_lds((__attribute__((address_space(1))) void*)g,
                                   (__attribute__((address_space(3))) void*)l,
                                   16, 0, 0);
}

// ---------------------------------------------------------------- prep
// One dispatch: blocks [0,16384) convert x fp32->fp16 (float4/thread);
// blocks [16384, 16384+576) do the 4 weight transposes (fp32->fp16, [R][C]->[C][R]).
__global__ __launch_bounds__(256)
void prep_kernel(const float* __restrict__ x, _Float16* __restrict__ x_h,
                 const float* __restrict__ Win, const float* __restrict__ Wout,
                 const float* __restrict__ Wgx, const float* __restrict__ Wga,
                 _Float16* __restrict__ WinT, _Float16* __restrict__ WoutT,
                 _Float16* __restrict__ WgxT, _Float16* __restrict__ WgaT) {
  __shared__ float tile[64][65];
  if (blockIdx.x < 16384) {
    const int gid = blockIdx.x * 256 + threadIdx.x;
    const float4 v = ((const float4*)x)[gid];
    half4v h;
    h[0] = (_Float16)v.x; h[1] = (_Float16)v.y; h[2] = (_Float16)v.z; h[3] = (_Float16)v.w;
    ((half4v*)x_h)[gid] = h;
    return;
  }
  int t = blockIdx.x - 16384;
  const float* src; _Float16* dst; int C; size_t bo = 0;
  if (t < 256)      { src = Win;  dst = WinT;  C = 1024; }
  else if (t < 512) { src = Wout; dst = WoutT; C = 1024; t -= 256; }
  else if (t < 544) { int u = t - 512; src = Wgx; dst = WgxT; C = 128;
                      bo = (size_t)(u >> 2) * (128 * 128); t = u & 3; }
  else              { int u = t - 544; src = Wga; dst = WgaT; C = 128;
                      bo = (size_t)(u >> 2) * (128 * 128); t = u & 3; }
  const int nbx = C >> 6;
  const int r0 = (t / nbx) * 64, c0 = (t % nbx) * 64;
  const int tr = threadIdx.x >> 6, tc = threadIdx.x & 63;
#pragma unroll
  for (int i = 0; i < 64; i += 4)
    tile[tr + i][tc] = src[bo + (size_t)(r0 + tr + i) * C + c0 + tc];
  __syncthreads();
#pragma unroll
  for (int i = 0; i < 64; i += 4) {
    const int cc = i + tr;
    dst[bo + (size_t)(c0 + cc) * C + r0 + tc] = (_Float16)tile[tc][cc];
  }
}

// ---------------------------------------------------------------- GEMM (m97 recipe)
// C[M,N] = A[M,K] * Bt[N,K]^T + bias ; 128x128 tile, 4 waves, BK=64, f16 MFMA.
// Epilogue stores j-INNERMOST: 4 stores cover contiguous 64 elems -> full-line
// sector merge survives the concurrent main-loop L2 churn.
template <int OUT_F32>
__global__ __launch_bounds__(256)
void gemm_bt(const _Float16* __restrict__ A, const _Float16* __restrict__ Bt,
             const float* __restrict__ bias, void* __restrict__ C,
             int M, int N, int K) {
  __shared__ __align__(16) _Float16 As[128 * 64];
  __shared__ __align__(16) _Float16 Bs[128 * 64];
  const int tid = threadIdx.x;
  const int wave = tid >> 6, lane = tid & 63;
  const int m0 = blockIdx.x * 128, n0 = blockIdx.y * 128;
  const int wm = (wave >> 1) * 64, wn = (wave & 1) * 64;
  const int row = lane & 15, quad = lane >> 4;
  const int srow = lane >> 3, scol = (lane & 7) * 8;

  f32x4 acc[4][4] = {};
  for (int kt = 0; kt < K; kt += 64) {
#pragma unroll
    for (int ci = 0; ci < 4; ci++) {
      const int c = wave * 4 + ci;
      gl_lds16(A  + (size_t)(m0 + c * 8 + srow) * K + kt + scol, As + c * 512);
      gl_lds16(Bt + (size_t)(n0 + c * 8 + srow) * K + kt + scol, Bs + c * 512);
    }
    __syncthreads();
#pragma unroll
    for (int kk = 0; kk < 64; kk += 32) {
      half8 af[4], bf[4];
#pragma unroll
      for (int i = 0; i < 4; i++)
        af[i] = *(const half8*)&As[(wm + i * 16 + row) * 64 + kk + quad * 8];
#pragma unroll
      for (int i = 0; i < 4; i++)
        bf[i] = *(const half8*)&Bs[(wn + i * 16 + row) * 64 + kk + quad * 8];
#pragma unroll
      for (int i = 0; i < 4; i++)
#pragma unroll
        for (int j = 0; j < 4; j++)
          acc[i][j] = __builtin_amdgcn_mfma_f32_16x16x32_f16(af[i], bf[j], acc[i][j], 0, 0, 0);
    }
    __syncthreads();
  }
  float bv[4];
#pragma unroll
  for (int j = 0; j < 4; j++) bv[j] = bias[n0 + wn + j * 16 + row];
#pragma unroll
  for (int i = 0; i < 4; i++) {
#pragma unroll
    for (int r = 0; r < 4; r++) {
      const int m = m0 + wm + i * 16 + quad * 4 + r;
      const size_t base = (size_t)m * N + n0 + wn + row;
#pragma unroll
      for (int j = 0; j < 4; j++) {
        const float v = acc[i][j][r] + bv[j];
        if (OUT_F32) ((float*)C)[base + j * 16] = v;
        else         ((_Float16*)C)[base + j * 16] = (_Float16)v;
      }
    }
  }
}

// ---------------------------------------------------------------- gates v3
// One block = 128 tokens x one 128-ch diag gate block. ZERO LDS, zero barriers:
// A-frags + xv from global (coalesced 64B segments; tile 32KB L1-resident,
// weights 64KB/nb L2-resident). NO launch_bounds cap: needs ~160 VGPR for the
// 32 accumulators — capping forces scratch spills (R4: 450MB phantom traffic).
// Fused per-chunk (A,h) reduction (scan p1) + inline softplus + j-inner stores.
__global__ __launch_bounds__(256)
void gates_v3(const _Float16* __restrict__ xp,
              const _Float16* __restrict__ WxT, const _Float16* __restrict__ WaT,
              const float* __restrict__ bgx, const float* __restrict__ bga,
              const float* __restrict__ arp,
              _Float16* __restrict__ a_out, _Float16* __restrict__ gx_out,
              float* __restrict__ cA, float* __restrict__ cH) {
  const int tid = threadIdx.x;
  const int wave = tid >> 6, lane = tid & 63;
  const int m0 = blockIdx.x * 128, nb = blockIdx.y;
  const int wm = (wave >> 1) * 64, wn = (wave & 1) * 64;
  const int row = lane & 15, quad = lane >> 4;
  const _Float16* WxB = WxT + (size_t)nb * (128 * 128);
  const _Float16* WaB = WaT + (size_t)nb * (128 * 128);
  const _Float16* xb = xp + (size_t)m0 * DH + nb * 128;   // block's xp tile

  f32x4 accx[4][4] = {}, acca[4][4] = {};
#pragma unroll
  for (int kk = 0; kk < 128; kk += 32) {
    half8 af[4];
#pragma unroll
    for (int i = 0; i < 4; i++)
      af[i] = *(const half8*)&xb[(size_t)(wm + i * 16 + row) * DH + kk + quad * 8];
#pragma unroll
    for (int j = 0; j < 4; j++) {
      const size_t wo = (size_t)(wn + j * 16 + row) * 128 + kk + quad * 8;
      const half8 bx = *(const half8*)&WxB[wo];
      const half8 ba = *(const half8*)&WaB[wo];
#pragma unroll
      for (int i = 0; i < 4; i++) {
        accx[i][j] = __builtin_amdgcn_mfma_f32_16x16x32_f16(af[i], bx, accx[i][j], 0, 0, 0);
        acca[i][j] = __builtin_amdgcn_mfma_f32_16x16x32_f16(af[i], ba, acca[i][j], 0, 0, 0);
      }
    }
  }

  // epilogue: gate math + fused per-chunk (A,h) reduction (replaces scan p1)
  const int b_idx = (m0 + wm) >> 12;
  const int c_idx = ((m0 + wm) & (SEQ - 1)) >> 6;
  float bxv[4], bav[4], cd[4];
#pragma unroll
  for (int j = 0; j < 4; j++) {
    const int d = nb * 128 + wn + j * 16 + row;
    bxv[j] = bgx[d]; bav[j] = bga[d];
    cd[j] = log1pf(expf(arp[d]));   // softplus inline
  }
  float Arun[4], Hrun[4];
#pragma unroll
  for (int j = 0; j < 4; j++) { Arun[j] = 1.f; Hrun[j] = 0.f; }

#pragma unroll
  for (int i = 0; i < 4; i++) {
    float Aseg[4], Hseg[4];
#pragma unroll
    for (int j = 0; j < 4; j++) { Aseg[j] = 1.f; Hseg[j] = 0.f; }
#pragma unroll
    for (int r = 0; r < 4; r++) {
      const int tl = wm + i * 16 + quad * 4 + r;
      const size_t rowbase = (size_t)(m0 + tl) * DH + nb * 128 + wn + row;
      _Float16 ah[4], gh[4];
#pragma unroll
      for (int j = 0; j < 4; j++) {
        const float px = accx[i][j][r] + bxv[j];
        const float pa = acca[i][j][r] + bav[j];
        const float sx = 1.f / (1.f + __expf(-px));
        const float sa = 1.f / (1.f + __expf(-pa));
        const float a = __expf(-8.f * sa * cd[j]);
        const float n2 = fmaxf(1.f - a * a, 0.f);
        const float xv = (float)xb[(size_t)tl * DH + wn + j * 16 + row];
        ah[j] = (_Float16)a;
        gh[j] = (_Float16)(sx * xv * sqrtf(n2));
        const float ar = (float)ah[j], gr = (float)gh[j];   // rounded, matches p3
        Aseg[j] *= ar;
        Hseg[j] = fmaf(ar, Hseg[j], gr);
      }
#pragma unroll
      for (int j = 0; j < 4; j++) a_out[rowbase + j * 16] = ah[j];
#pragma unroll
      for (int j = 0; j < 4; j++) gx_out[rowbase + j * 16] = gh[j];
    }
    // cross-quad combine (token order q0..q3), fold into running
#pragma unroll
    for (int j = 0; j < 4; j++) {
      float A1 = Aseg[j], H1 = Hseg[j];
      float A2 = __shfl_down(A1, 16, 64), H2 = __shfl_down(H1, 16, 64);
      H1 = fmaf(A2, H1, H2); A1 *= A2;
      A2 = __shfl_down(A1, 32, 64); H2 = __shfl_down(H1, 32, 64);
      H1 = fmaf(A2, H1, H2); A1 *= A2;
      Hrun[j] = fmaf(A1, Hrun[j], H1);
      Arun[j] *= A1;
    }
  }
  // carry store, [c][g] layout: 16 lanes x 4B = 64B contiguous per j (no RMW)
  if (lane < 16) {
    const int base = c_idx * (B_SZ * DH) + b_idx * DH + nb * 128 + wn + lane;
#pragma unroll
    for (int j = 0; j < 4; j++) {
      cA[base + j * 16] = Arun[j];
      cH[base + j * 16] = Hrun[j];
    }
  }
}

// ---------------------------------------------------------------- scan p2/p3
// p2: one wave per channel g; lane = chunk. 6-step shfl inclusive scan with
// segment composition (A2*A1, A2*H1+H2); exclusive shift gives chunk carry-in.
// Reads/writes are [c][g]-strided (16KB) but total volume is only ~12MB.
__global__ __launch_bounds__(256)
void scan_p2(const float* __restrict__ cA, const float* __restrict__ cH,
             const float* __restrict__ h0, float* __restrict__ cin,
             float* __restrict__ hlast) {
  const int wave = threadIdx.x >> 6, lane = threadIdx.x & 63;
  const int g = blockIdx.x * 4 + wave;   // [0, B_SZ*DH)
  float A = cA[(size_t)lane * (B_SZ * DH) + g], H = cH[(size_t)lane * (B_SZ * DH) + g];
#pragma unroll
  for (int d = 1; d < 64; d <<= 1) {
    const float Ap = __shfl_up(A, d, 64), Hp = __shfl_up(H, d, 64);
    if (lane >= d) { H = fmaf(A, Hp, H); A *= Ap; }
  }
  const float h0g = h0[g];
  if (lane == 63) hlast[g] = fmaf(A, h0g, H);
  float Ae = __shfl_up(A, 1, 64), He = __shfl_up(H, 1, 64);
  if (lane == 0) { Ae = 1.f; He = 0.f; }
  cin[(size_t)lane * (B_SZ * DH) + g] = fmaf(Ae, h0g, He);
}

__global__ __launch_bounds__(256)
void scan_p3(const _Float16* __restrict__ a, const _Float16* __restrict__ gx,
             const float* __restrict__ cin, _Float16* __restrict__ h) {
  const int gtid = blockIdx.x * 256 + threadIdx.x;
  const int d = gtid & (DH - 1);
  const int bc = gtid >> 10;
  const int b = bc >> 6, c = bc & (NCHUNK - 1);
  const size_t base = ((size_t)(b * SEQ + c * CHUNK)) * DH + d;
  float carry = cin[c * (B_SZ * DH) + b * DH + d];   // block = 256 consecutive d -> coalesced
#pragma unroll 4
  for (int i = 0; i < CHUNK; i++) {
    const float av = (float)a[base + (size_t)i * DH];
    const float gv = (float)gx[base + (size_t)i * DH];
    carry = fmaf(av, carry, gv);
    h[base + (size_t)i * DH] = (_Float16)carry;
  }
}

// ---------------------------------------------------------------- launch
extern "C" void kernel_launch(void* const* d_in, const int* in_sizes, int n_in,
                              void* d_out, int out_size, void* d_ws, size_t ws_size,
                              hipStream_t stream) {
  const float* x     = (const float*)d_in[0];
  const float* h0    = (const float*)d_in[1];
  const float* W_in  = (const float*)d_in[2];
  const float* b_in  = (const float*)d_in[3];
  const float* Wgx   = (const float*)d_in[4];
  const float* bgx   = (const float*)d_in[5];
  const float* Wga   = (const float*)d_in[6];
  const float* bga   = (const float*)d_in[7];
  const float* arp   = (const float*)d_in[8];
  const float* W_out = (const float*)d_in[9];
  const float* b_out = (const float*)d_in[10];
  float* out = (float*)d_out;
  float* hlast = out + (size_t)MTOK * DOUT;

  char* p = (char*)d_ws;
  auto take = [&](size_t bytes) { char* r = p; p += (bytes + 255) & ~(size_t)255; return r; };
  _Float16* x_h   = (_Float16*)take((size_t)MTOK * DIN * 2);   // reused as h_buf
  _Float16* xp    = (_Float16*)take((size_t)MTOK * DH * 2);
  _Float16* a_buf = (_Float16*)take((size_t)MTOK * DH * 2);
  _Float16* gxb   = (_Float16*)take((size_t)MTOK * DH * 2);
  _Float16* WinT  = (_Float16*)take((size_t)DIN * DH * 2);
  _Float16* WoutT = (_Float16*)take((size_t)DH * DOUT * 2);
  _Float16* WgxT  = (_Float16*)take((size_t)NBLK * 128 * 128 * 2);
  _Float16* WgaT  = (_Float16*)take((size_t)NBLK * 128 * 128 * 2);
  float* cA   = (float*)take((size_t)NCHUNK * B_SZ * DH * 4);
  float* cH   = (float*)take((size_t)NCHUNK * B_SZ * DH * 4);
  float* cin  = (float*)take((size_t)NCHUNK * B_SZ * DH * 4);
  _Float16* h_buf = x_h;   // x_h dead after gemm1

  prep_kernel<<<16384 + 576, 256, 0, stream>>>(x, x_h, W_in, W_out, Wgx, Wga,
                                               WinT, WoutT, WgxT, WgaT);
  gemm_bt<0><<<dim3(MTOK / 128, DH / 128), 256, 0, stream>>>(x_h, WinT, b_in, xp, MTOK, DH, DIN);
  gates_v3<<<dim3(MTOK / 128, NBLK), 256, 0, stream>>>(
      xp, WgxT, WgaT, bgx, bga, arp, a_buf, gxb, cA, cH);
  scan_p2<<<(B_SZ * DH) / 4, 256, 0, stream>>>(cA, cH, h0, cin, hlast);
  scan_p3<<<(B_SZ * NCHUNK * DH) / 256, 256, 0, stream>>>(a_buf, gxb, cin, h_buf);
  gemm_bt<1><<<dim3(MTOK / 128, DOUT / 128), 256, 0, stream>>>(h_buf, WoutT, b_out, out, MTOK, DOUT, DH);
}